// Round 5
// baseline (3629.711 us; speedup 1.0000x reference)
//
#include <hip/hip_runtime.h>
#include <hip/hip_bf16.h>
#include <cstdint>
#include <cstddef>

#define HH 64
#define BB 256
#define TT 200
#define DL 711
#define DA 300
#define DV 74
#define DD 1085
#define GXW 768                    // 3 * 4H
#define NROW (TT * BB)             // 51200
#define HPOFF ((size_t)NROW * GXW) // float offset of h-partials in ws

// gx row (t,b) column layout through the phases:
//  Phase A writes gates_x: L gates 0..256, A gates 256..512, V gates 512..768
//  Phase B (step t) consumes gates of row t, then stashes (per modality m):
//    c_t    -> m*256 + 0  .. +64
//    c_{t+1}-> m*256 + 64 .. +128
//  Phase C writes: chat -> 192..256, PRE1 -> 384..448, PRE2 -> 448..512
//  Phase D reads chat/PRE1/PRE2 + hp; writes out.

// ---------------------------------------------------------------------------
// Phase A: input projections gx = x @ wih for all (t,b). Unchanged (verified).
// ---------------------------------------------------------------------------
__global__ __launch_bounds__(256) void proj_kernel(
    const float* __restrict__ x,
    const float* __restrict__ wl,
    const float* __restrict__ wa,
    const float* __restrict__ wv,
    float* __restrict__ gx)
{
    const int mod = blockIdx.y;
    const int K   = (mod == 0) ? DL : (mod == 1 ? DA : DV);
    const int off = (mod == 0) ? 0  : (mod == 1 ? DL : (DL + DA));
    const float* __restrict__ W = (mod == 0) ? wl : (mod == 1 ? wa : wv);

    const int tid = threadIdx.x;
    const int r0  = blockIdx.x * 64;

    __shared__ float As[32][65];
    __shared__ float Bs[32][256];

    const int tm = (tid >> 5) << 3;
    const int tn = (tid & 31) << 3;

    const int am = tid >> 2;
    const int ad = (tid & 3) << 3;
    const int r  = r0 + am;
    const int b  = r & 255;
    const int t  = r >> 8;
    const float* __restrict__ xrow = x + ((size_t)b * TT + t) * DD + off;

    const int bk = tid >> 3;
    const int bf = tid & 7;

    float acc[8][8];
    #pragma unroll
    for (int i = 0; i < 8; ++i)
        #pragma unroll
        for (int j = 0; j < 8; ++j) acc[i][j] = 0.f;

    for (int k0 = 0; k0 < K; k0 += 32) {
        #pragma unroll
        for (int u = 0; u < 8; ++u) {
            int d = k0 + ad + u;
            As[ad + u][am] = (d < K) ? xrow[d] : 0.f;
        }
        {
            const bool kin = (k0 + bk) < K;
            const float4* __restrict__ wrow4 =
                (const float4*)(W + (size_t)(k0 + bk) * 256);
            #pragma unroll
            for (int u = 0; u < 8; ++u) {
                int c4 = bf + u * 8;
                float4 v = kin ? wrow4[c4] : make_float4(0.f, 0.f, 0.f, 0.f);
                *(float4*)&Bs[bk][c4 << 2] = v;
            }
        }
        __syncthreads();

        #pragma unroll
        for (int kk = 0; kk < 32; ++kk) {
            float a[8], bb[8];
            #pragma unroll
            for (int i = 0; i < 8; ++i) a[i] = As[kk][tm + i];
            float4 b0 = *(const float4*)&Bs[kk][tn];
            float4 b1 = *(const float4*)&Bs[kk][tn + 4];
            bb[0] = b0.x; bb[1] = b0.y; bb[2] = b0.z; bb[3] = b0.w;
            bb[4] = b1.x; bb[5] = b1.y; bb[6] = b1.z; bb[7] = b1.w;
            #pragma unroll
            for (int i = 0; i < 8; ++i)
                #pragma unroll
                for (int j = 0; j < 8; ++j)
                    acc[i][j] += a[i] * bb[j];
        }
        __syncthreads();
    }

    #pragma unroll
    for (int i = 0; i < 8; ++i) {
        size_t row = (size_t)(r0 + tm + i);
        float* o = gx + row * GXW + mod * 256 + tn;
        *(float4*)&o[0] = make_float4(acc[i][0], acc[i][1], acc[i][2], acc[i][3]);
        *(float4*)&o[4] = make_float4(acc[i][4], acc[i][5], acc[i][6], acc[i][7]);
    }
}

// ---------------------------------------------------------------------------
// Phase B: 3 independent LSTM chains. One wave per block, 2 batch rows per
// wave, whh in LDS (loaded once, gate-interleaved for ds_read_b128), h/c in
// registers, h-broadcast via __shfl. Zero barriers in the 200-step loop.
// Grid: 384 blocks = 3 modalities x 128 row-pairs.
// ---------------------------------------------------------------------------
__global__ __launch_bounds__(64) void lstm_kernel(
    float* gx,                          // read gates + write stash (same buf)
    const float* __restrict__ whhl,
    const float* __restrict__ whha,
    const float* __restrict__ whhv,
    const float* __restrict__ ow1,
    float* __restrict__ hp)
{
    const int blk = blockIdx.x;
    const int m   = blk >> 7;           // 0..2
    const int b0  = (blk & 127) * 2;    // rows b0, b0+1
    const int j   = threadIdx.x;        // 0..63 = gate column
    const float* __restrict__ W = (m == 0) ? whhl : ((m == 1) ? whha : whhv);

    // Wi[i][j] = { W[i][j], W[i][64+j], W[i][128+j], W[i][192+j] }  (64 KB)
    __shared__ float4 Wi[64][64];
    #pragma unroll 4
    for (int i = 0; i < 64; ++i) {
        const float* wr = W + i * 256 + j;
        Wi[i][j] = make_float4(wr[0], wr[64], wr[128], wr[192]);
    }
    // single wave: ds_write->ds_read ordered by lgkmcnt, no barrier needed

    float h0 = 0.f, h1 = 0.f, c0 = 0.f, c1 = 0.f;

    // prefetch t=0 gate-x values
    float g0[4], g1[4];
    {
        const float* p = gx + ((size_t)b0) * GXW + m * 256 + j;
        #pragma unroll
        for (int g = 0; g < 4; ++g) { g0[g] = p[g * 64]; g1[g] = p[GXW + g * 64]; }
    }

    for (int t = 0; t < TT; ++t) {
        float a0[4], a1[4];
        #pragma unroll
        for (int g = 0; g < 4; ++g) { a0[g] = g0[g]; a1[g] = g1[g]; }

        #pragma unroll
        for (int i = 0; i < 64; ++i) {
            float4 wv = Wi[i][j];
            float hv0 = __shfl(h0, i);
            float hv1 = __shfl(h1, i);
            a0[0] += hv0 * wv.x; a0[1] += hv0 * wv.y;
            a0[2] += hv0 * wv.z; a0[3] += hv0 * wv.w;
            a1[0] += hv1 * wv.x; a1[1] += hv1 * wv.y;
            a1[2] += hv1 * wv.z; a1[3] += hv1 * wv.w;
        }

        // prefetch next step's gate-x
        if (t + 1 < TT) {
            const float* p = gx + ((size_t)(t + 1) * BB + b0) * GXW + m * 256 + j;
            #pragma unroll
            for (int g = 0; g < 4; ++g) { g0[g] = p[g * 64]; g1[g] = p[GXW + g * 64]; }
        }

        // activations + cell update (lane j = cell j)
        float iv0 = 1.f / (1.f + expf(-a0[0]));
        float fv0 = 1.f / (1.f + expf(-a0[1]));
        float gv0 = tanhf(a0[2]);
        float ov0 = 1.f / (1.f + expf(-a0[3]));
        float iv1 = 1.f / (1.f + expf(-a1[0]));
        float fv1 = 1.f / (1.f + expf(-a1[1]));
        float gv1 = tanhf(a1[2]);
        float ov1 = 1.f / (1.f + expf(-a1[3]));

        float cn0 = fv0 * c0 + iv0 * gv0;
        float cn1 = fv1 * c1 + iv1 * gv1;

        // stash c_t and c_{t+1} into gx row t (cols m*256 + [0,128))
        float* grow = gx + ((size_t)t * BB + b0) * GXW + m * 256;
        grow[j]            = c0;
        grow[64 + j]       = cn0;
        grow[GXW + j]      = c1;
        grow[GXW + 64 + j] = cn1;

        c0 = cn0; c1 = cn1;
        h0 = ov0 * tanhf(cn0);
        h1 = ov1 * tanhf(cn1);
    }

    // h-partial: hp[(m*256+b)*64+j] = sum_i h[b][i] * ow1[(m*64+i)*64+j]
    {
        float s0 = 0.f, s1 = 0.f;
        #pragma unroll 8
        for (int i = 0; i < 64; ++i) {
            float w = ow1[(m * 64 + i) * 64 + j];
            s0 += __shfl(h0, i) * w;
            s1 += __shfl(h1, i) * w;
        }
        hp[((size_t)m * BB + b0) * 64 + j]     = s0;
        hp[((size_t)m * BB + b0 + 1) * 64 + j] = s1;
    }
}

// ---------------------------------------------------------------------------
// Phase C: batched attention path for all 51200 rows. 32 rows/block,
// 256 threads. Computes A1, softmax, attended, then chat/PRE1/PRE2.
// ---------------------------------------------------------------------------
__global__ __launch_bounds__(256) void att_kernel(
    float* gx,
    const float* __restrict__ a1w1, const float* __restrict__ a1b1,
    const float* __restrict__ a1w2, const float* __restrict__ a1b2,
    const float* __restrict__ a2w1, const float* __restrict__ a2b1,
    const float* __restrict__ a2w2, const float* __restrict__ a2b2,
    const float* __restrict__ g1w1, const float* __restrict__ g1b1,
    const float* __restrict__ g2w1, const float* __restrict__ g2b1)
{
    const int tid = threadIdx.x;
    const size_t R0 = (size_t)blockIdx.x * 32;

    __shared__ float cs[32][384];   // c_star, later attended (in-place)
    __shared__ float hb[32][64];    // A1, later A2

    // load c_star (scattered col map -> logical order [c_l c_a c_v nc_l nc_a nc_v])
    for (int u = 0; u < 48; ++u) {
        int flat = tid + u * 256;           // 0..12287
        int rr = flat / 384;
        int i  = flat - rr * 384;
        int col;
        if (i < 192) col = (i >> 6) * 256 + (i & 63);
        else { int jj = i - 192; col = (jj >> 6) * 256 + 64 + (jj & 63); }
        cs[rr][i] = gx[(R0 + rr) * GXW + col];
    }
    __syncthreads();

    const int j   = tid & 63;
    const int rrg = tid >> 6;              // row group: rows rrg*8 .. +7

    // A1 = relu(cs @ a1w1 + b1)
    {
        float acc[8];
        #pragma unroll
        for (int u = 0; u < 8; ++u) acc[u] = a1b1[j];
        for (int i = 0; i < 384; ++i) {
            float w = a1w1[i * 64 + j];
            #pragma unroll
            for (int u = 0; u < 8; ++u) acc[u] += cs[rrg * 8 + u][i] * w;
        }
        #pragma unroll
        for (int u = 0; u < 8; ++u) hb[rrg * 8 + u][j] = fmaxf(acc[u], 0.f);
    }
    __syncthreads();

    // scores + softmax + attended (per wave: 8 rows, weight loads amortized)
    {
        const int lane = tid & 63;
        float sc[6][8];
        #pragma unroll
        for (int q = 0; q < 6; ++q) {
            float bv = a1b2[lane + q * 64];
            #pragma unroll
            for (int u = 0; u < 8; ++u) sc[q][u] = bv;
        }
        for (int i = 0; i < 64; ++i) {
            float av[8];
            #pragma unroll
            for (int u = 0; u < 8; ++u) av[u] = hb[rrg * 8 + u][i];
            #pragma unroll
            for (int q = 0; q < 6; ++q) {
                float w = a1w2[i * 384 + lane + q * 64];
                #pragma unroll
                for (int u = 0; u < 8; ++u) sc[q][u] += av[u] * w;
            }
        }
        #pragma unroll
        for (int u = 0; u < 8; ++u) {
            const int r = rrg * 8 + u;
            float mx = sc[0][u];
            #pragma unroll
            for (int q = 1; q < 6; ++q) mx = fmaxf(mx, sc[q][u]);
            #pragma unroll
            for (int o = 32; o > 0; o >>= 1) mx = fmaxf(mx, __shfl_xor(mx, o));
            float sm = 0.f;
            float e[6];
            #pragma unroll
            for (int q = 0; q < 6; ++q) { e[q] = expf(sc[q][u] - mx); sm += e[q]; }
            #pragma unroll
            for (int o = 32; o > 0; o >>= 1) sm += __shfl_xor(sm, o);
            float inv = 1.f / sm;
            #pragma unroll
            for (int q = 0; q < 6; ++q) {
                int L = lane + q * 64;
                cs[r][L] = e[q] * inv * cs[r][L];
            }
        }
    }
    __syncthreads();

    // A2 / PRE1 / PRE2 (attended @ {a2w1, g1w1[0:384], g2w1[0:384]} + biases)
    {
        float sa[8], s1[8], s2[8];
        #pragma unroll
        for (int u = 0; u < 8; ++u) { sa[u] = a2b1[j]; s1[u] = g1b1[j]; s2[u] = g2b1[j]; }
        for (int i = 0; i < 384; ++i) {
            float wa = a2w1[i * 64 + j];
            float w1 = g1w1[i * 64 + j];
            float w2 = g2w1[i * 64 + j];
            #pragma unroll
            for (int u = 0; u < 8; ++u) {
                float v = cs[rrg * 8 + u][i];
                sa[u] += v * wa; s1[u] += v * w1; s2[u] += v * w2;
            }
        }
        #pragma unroll
        for (int u = 0; u < 8; ++u) {
            const size_t r = R0 + rrg * 8 + u;
            float* grow = gx + r * GXW;
            grow[384 + j] = s1[u];      // PRE1
            grow[448 + j] = s2[u];      // PRE2
            hb[rrg * 8 + u][j] = fmaxf(sa[u], 0.f);   // A2 (overwrite A1)
        }
    }
    __syncthreads();

    // chat = tanh(A2 @ a2w2 + b2)
    {
        float acc[8];
        #pragma unroll
        for (int u = 0; u < 8; ++u) acc[u] = a2b2[j];
        for (int i = 0; i < 64; ++i) {
            float w = a2w2[i * 64 + j];
            #pragma unroll
            for (int u = 0; u < 8; ++u) acc[u] += hb[rrg * 8 + u][i] * w;
        }
        #pragma unroll
        for (int u = 0; u < 8; ++u)
            gx[(R0 + rrg * 8 + u) * GXW + 192 + j] = tanhf(acc[u]);
    }
}

// ---------------------------------------------------------------------------
// Phase D: sequential mem recurrence. 256 blocks x 64 threads (1 wave, no
// barriers in the loop). All 4 weight mats in LDS (64 KB), loaded once.
// ---------------------------------------------------------------------------
__global__ __launch_bounds__(64) void mem_kernel(
    const float* __restrict__ gx,
    const float* __restrict__ g1w1, const float* __restrict__ g1w2, const float* __restrict__ g1b2,
    const float* __restrict__ g2w1, const float* __restrict__ g2w2, const float* __restrict__ g2b2,
    const float* __restrict__ ow1,  const float* __restrict__ ow2,
    const float* __restrict__ hp,
    float* __restrict__ out)
{
    const int j = threadIdx.x;
    const int b = blockIdx.x;

    __shared__ float Wm1[64][64];
    __shared__ float Wm2[64][64];
    __shared__ float Wf1[64][64];
    __shared__ float Wf2[64][64];

    for (int i = 0; i < 64; ++i) {
        Wm1[i][j] = g1w1[(384 + i) * 64 + j];
        Wm2[i][j] = g2w1[(384 + i) * 64 + j];
        Wf1[i][j] = g1w2[i * 64 + j];
        Wf2[i][j] = g2w2[i * 64 + j];
    }
    const float bf1 = g1b2[j], bf2 = g2b2[j];
    __syncthreads();

    float mem = 0.f;
    const float* base0 = gx + (size_t)b * GXW;
    float cj = base0[192 + j];
    float p1 = base0[384 + j];
    float p2 = base0[448 + j];

    for (int t = 0; t < TT; ++t) {
        float ncj = 0.f, np1 = 0.f, np2 = 0.f;
        if (t + 1 < TT) {
            const float* nb = gx + ((size_t)(t + 1) * BB + b) * GXW;
            ncj = nb[192 + j]; np1 = nb[384 + j]; np2 = nb[448 + j];
        }
        // hid = relu(PRE + mem @ Wm)
        float s1 = p1, s2 = p2;
        #pragma unroll 8
        for (int i = 0; i < 64; ++i) {
            float mv = __shfl(mem, i);
            s1 += mv * Wm1[i][j];
            s2 += mv * Wm2[i][j];
        }
        float h1 = fmaxf(s1, 0.f);
        float h2 = fmaxf(s2, 0.f);
        // gamma = sigmoid(hid @ Wf + b2)
        float t1 = bf1, t2 = bf2;
        #pragma unroll 8
        for (int i = 0; i < 64; ++i) {
            t1 += __shfl(h1, i) * Wf1[i][j];
            t2 += __shfl(h2, i) * Wf2[i][j];
        }
        float g1 = 1.f / (1.f + expf(-t1));
        float g2 = 1.f / (1.f + expf(-t2));
        mem = g1 * mem + g2 * cj;
        cj = ncj; p1 = np1; p2 = np2;
    }

    // out[b] = relu([h_l h_a h_v mem] @ ow1) @ ow2
    float s = hp[((size_t)0 * BB + b) * 64 + j]
            + hp[((size_t)1 * BB + b) * 64 + j]
            + hp[((size_t)2 * BB + b) * 64 + j];
    #pragma unroll 8
    for (int i = 0; i < 64; ++i)
        s += __shfl(mem, i) * ow1[(192 + i) * 64 + j];
    float y = fmaxf(s, 0.f) * ow2[j];
    #pragma unroll
    for (int o = 32; o > 0; o >>= 1) y += __shfl_xor(y, o);
    if (j == 0) out[b] = y;
}

// ---------------------------------------------------------------------------
extern "C" void kernel_launch(void* const* d_in, const int* in_sizes, int n_in,
                              void* d_out, int out_size, void* d_ws, size_t ws_size,
                              hipStream_t stream)
{
    const float* x    = (const float*)d_in[0];
    const float* wihl = (const float*)d_in[1];
    const float* whhl = (const float*)d_in[2];
    const float* wiha = (const float*)d_in[3];
    const float* whha = (const float*)d_in[4];
    const float* wihv = (const float*)d_in[5];
    const float* whhv = (const float*)d_in[6];
    const float* a1w1 = (const float*)d_in[7];
    const float* a1b1 = (const float*)d_in[8];
    const float* a1w2 = (const float*)d_in[9];
    const float* a1b2 = (const float*)d_in[10];
    const float* a2w1 = (const float*)d_in[11];
    const float* a2b1 = (const float*)d_in[12];
    const float* a2w2 = (const float*)d_in[13];
    const float* a2b2 = (const float*)d_in[14];
    const float* g1w1 = (const float*)d_in[15];
    const float* g1b1 = (const float*)d_in[16];
    const float* g1w2 = (const float*)d_in[17];
    const float* g1b2 = (const float*)d_in[18];
    const float* g2w1 = (const float*)d_in[19];
    const float* g2b1 = (const float*)d_in[20];
    const float* g2w2 = (const float*)d_in[21];
    const float* g2b2 = (const float*)d_in[22];
    const float* ow1  = (const float*)d_in[23];
    const float* ow2  = (const float*)d_in[24];

    float* gx  = (float*)d_ws;             // 51200*768 floats = 157.3 MB
    float* hp  = (float*)d_ws + HPOFF;     // 3*256*64 floats  = 196 KB
    float* out = (float*)d_out;

    proj_kernel<<<dim3(800, 3, 1), dim3(256, 1, 1), 0, stream>>>(
        x, wihl, wiha, wihv, gx);

    lstm_kernel<<<dim3(384, 1, 1), dim3(64, 1, 1), 0, stream>>>(
        gx, whhl, whha, whhv, ow1, hp);

    att_kernel<<<dim3(1600, 1, 1), dim3(256, 1, 1), 0, stream>>>(
        gx,
        a1w1, a1b1, a1w2, a1b2,
        a2w1, a2b1, a2w2, a2b2,
        g1w1, g1b1, g2w1, g2b1);

    mem_kernel<<<dim3(256, 1, 1), dim3(64, 1, 1), 0, stream>>>(
        gx, g1w1, g1w2, g1b2, g2w1, g2w2, g2b2, ow1, ow2, hp, out);
}